// Round 1
// baseline (397.182 us; speedup 1.0000x reference)
//
#include <hip/hip_runtime.h>
#include <math.h>

// GraphConvolution (GCNII variant=True, residual=True)
//   agg[dst] += h[src] * edge_w          (SpMM, atomic scatter)
//   out = theta*(agg@W1 + i@W2) + (1-theta)*((1-alpha)*agg + alpha*i) + i
// N=100000, E=1000000, D=D_OUT=64, weight is [128,64] row-major.

#define DFEAT 64

__device__ inline float lane_bcast(float v, int l) {
    return __uint_as_float(__builtin_amdgcn_readlane(__float_as_uint(v), l));
}

// One wave (64 lanes) per edge; lane = feature index.
__global__ __launch_bounds__(256) void spmm_scatter_kernel(
    const float* __restrict__ h,
    const float* __restrict__ edge_w,
    const int* __restrict__ edge_src,
    const int* __restrict__ edge_dst,
    float* __restrict__ agg,
    int E) {
    int gid = blockIdx.x * 256 + threadIdx.x;
    int lane = threadIdx.x & 63;
    // wave-uniform edge id (readfirstlane -> scalar loads for src/dst/w)
    int e = __builtin_amdgcn_readfirstlane(gid >> 6);
    if (e >= E) return;
    int s = edge_src[e];
    int d = edge_dst[e];
    float w = edge_w[e];
    float val = h[(size_t)s * DFEAT + lane] * w;
    atomicAdd(&agg[(size_t)d * DFEAT + lane], val);
}

// One wave per row. W (128x64 fp32 = 32 KB) staged in LDS.
// Lane j computes out[r][j] = theta * sum_k row[k]*W[k][j] + mix terms.
__global__ __launch_bounds__(256) void epilogue_kernel(
    const float* __restrict__ agg,
    const float* __restrict__ ifeat,
    const float* __restrict__ weight,   // [128][64] row-major
    const float* __restrict__ lamda_p,
    const float* __restrict__ alpha_p,
    const int* __restrict__ layer_p,
    float* __restrict__ out,
    int N) {
    __shared__ float Ws[128 * DFEAT];

    // cooperative load of W into LDS (coalesced)
    for (int idx = threadIdx.x; idx < 128 * DFEAT; idx += 256) {
        Ws[idx] = weight[idx];
    }
    __syncthreads();

    float lam = lamda_p[0];
    float alpha = alpha_p[0];
    float layer = (float)layer_p[0];
    float theta = fminf(1.0f, logf(lam / layer + 1.0f));

    int lane = threadIdx.x & 63;
    int r = __builtin_amdgcn_readfirstlane((blockIdx.x * 256 + threadIdx.x) >> 6);
    if (r >= N) return;

    float hv = agg[(size_t)r * DFEAT + lane];
    float iv = ifeat[(size_t)r * DFEAT + lane];

    float acc = 0.0f;
#pragma unroll
    for (int k = 0; k < 64; ++k) {
        acc += lane_bcast(hv, k) * Ws[k * DFEAT + lane];
    }
#pragma unroll
    for (int k = 0; k < 64; ++k) {
        acc += lane_bcast(iv, k) * Ws[(64 + k) * DFEAT + lane];
    }

    float rterm = (1.0f - alpha) * hv + alpha * iv;
    out[(size_t)r * DFEAT + lane] = theta * acc + (1.0f - theta) * rterm + iv;
}

extern "C" void kernel_launch(void* const* d_in, const int* in_sizes, int n_in,
                              void* d_out, int out_size, void* d_ws, size_t ws_size,
                              hipStream_t stream) {
    const float* h       = (const float*)d_in[0];
    const float* ifeat   = (const float*)d_in[1];
    const float* weight  = (const float*)d_in[2];
    const float* edge_w  = (const float*)d_in[3];
    const float* lamda_p = (const float*)d_in[4];
    const float* alpha_p = (const float*)d_in[5];
    const int*   e_src   = (const int*)d_in[6];
    const int*   e_dst   = (const int*)d_in[7];
    const int*   layer_p = (const int*)d_in[8];
    float* out = (float*)d_out;

    int N = in_sizes[0] / DFEAT;
    int E = in_sizes[3];

    float* agg = (float*)d_ws;  // N*64 fp32 = 25.6 MB

    // zero the aggregation buffer (ws is poisoned to 0xAA before each call)
    hipMemsetAsync(agg, 0, (size_t)N * DFEAT * sizeof(float), stream);

    // scatter: one wave per edge -> E waves -> E/4 blocks of 256
    int scatter_blocks = (E + 3) / 4;
    spmm_scatter_kernel<<<scatter_blocks, 256, 0, stream>>>(
        h, edge_w, e_src, e_dst, agg, E);

    // epilogue: one wave per row -> N/4 blocks of 256
    int epi_blocks = (N + 3) / 4;
    epilogue_kernel<<<epi_blocks, 256, 0, stream>>>(
        agg, ifeat, weight, lamda_p, alpha_p, layer_p, out, N);
}

// Round 2
// 323.696 us; speedup vs baseline: 1.2270x; 1.2270x over previous
//
#include <hip/hip_runtime.h>
#include <math.h>

// GraphConvolution (GCNII variant=True, residual=True), N=100k, E=1M, D=64.
//   agg[dst] += h[src] * edge_w      (CSR built on-device, gather-based SpMM)
//   out = theta*([agg,i]@W) + (1-theta)*((1-alpha)*agg + alpha*i) + i
//
// R2 design: atomic scatter (225us, L2-atomic-bound) replaced by
// histogram -> scan -> bucket-fill -> gather; LDS-bound epilogue (ds_read_b32
// per MAC, ~165us) replaced by register-resident W + readlane broadcast.

#define DFEAT 64

__device__ inline float lane_bcast(float v, int l) {
    return __uint_as_float(__builtin_amdgcn_readlane(__float_as_uint(v), l));
}

// ---- CSR build ----

__global__ __launch_bounds__(256) void hist_kernel(
    const int* __restrict__ dst, int* __restrict__ deg, int E) {
    int e = blockIdx.x * 256 + threadIdx.x;
    if (e < E) atomicAdd(&deg[dst[e]], 1);
}

// Per-block exclusive scan (1024 elems/block) -> cursor; block totals -> bsum.
__global__ __launch_bounds__(1024) void scan_block_kernel(
    const int* __restrict__ deg, int* __restrict__ cursor,
    int* __restrict__ bsum, int N) {
    __shared__ int tmp[1024];
    int tid = threadIdx.x;
    int i = blockIdx.x * 1024 + tid;
    int v = (i < N) ? deg[i] : 0;
    tmp[tid] = v;
    __syncthreads();
    for (int ofs = 1; ofs < 1024; ofs <<= 1) {
        int t = (tid >= ofs) ? tmp[tid - ofs] : 0;
        __syncthreads();
        tmp[tid] += t;
        __syncthreads();
    }
    if (i < N) cursor[i] = tmp[tid] - v;            // exclusive partial
    if (tid == 1023) bsum[blockIdx.x] = tmp[tid];   // block total
}

// Exclusive scan of block sums in place (nb <= 128).
__global__ __launch_bounds__(128) void scan_top_kernel(int* bsum, int nb) {
    __shared__ int tmp[128];
    int tid = threadIdx.x;
    int v = (tid < nb) ? bsum[tid] : 0;
    tmp[tid] = v;
    __syncthreads();
    for (int ofs = 1; ofs < 128; ofs <<= 1) {
        int t = (tid >= ofs) ? tmp[tid - ofs] : 0;
        __syncthreads();
        tmp[tid] += t;
        __syncthreads();
    }
    if (tid < nb) bsum[tid] = tmp[tid] - v;
}

__global__ __launch_bounds__(256) void apply_kernel(
    int* __restrict__ cursor, const int* __restrict__ bsum, int N) {
    int i = blockIdx.x * 256 + threadIdx.x;
    if (i < N) cursor[i] += bsum[i >> 10];
}

// Scatter edges into dst-buckets: packed[p] = (src, bits(w)).
__global__ __launch_bounds__(256) void fill_kernel(
    const int* __restrict__ src, const int* __restrict__ dst,
    const float* __restrict__ w, int* __restrict__ cursor,
    int2* __restrict__ packed, int E) {
    int e = blockIdx.x * 256 + threadIdx.x;
    if (e < E) {
        int d = dst[e];
        int p = atomicAdd(&cursor[d], 1);
        packed[p] = make_int2(src[e], __float_as_int(w[e]));
    }
}

// ---- gather SpMM: one wave per node, lane = feature ----
// After fill, cursor[n] == start(n) + deg(n), so start = cursor[n] - deg[n].
__global__ __launch_bounds__(256) void gather_kernel(
    const float* __restrict__ h, const int2* __restrict__ packed,
    const int* __restrict__ cursor, const int* __restrict__ deg,
    float* __restrict__ agg, int N) {
    int lane = threadIdx.x & 63;
    int n = (blockIdx.x * 256 + threadIdx.x) >> 6;
    if (n >= N) return;
    int dg = deg[n];
    int base = cursor[n] - dg;
    float acc = 0.f;
    int t = 0;
    for (; t + 4 <= dg; t += 4) {
        int2 p0 = packed[base + t];
        int2 p1 = packed[base + t + 1];
        int2 p2 = packed[base + t + 2];
        int2 p3 = packed[base + t + 3];
        float v0 = h[(size_t)p0.x * DFEAT + lane];
        float v1 = h[(size_t)p1.x * DFEAT + lane];
        float v2 = h[(size_t)p2.x * DFEAT + lane];
        float v3 = h[(size_t)p3.x * DFEAT + lane];
        acc += __int_as_float(p0.y) * v0;
        acc += __int_as_float(p1.y) * v1;
        acc += __int_as_float(p2.y) * v2;
        acc += __int_as_float(p3.y) * v3;
    }
    for (; t < dg; ++t) {
        int2 p = packed[base + t];
        acc += __int_as_float(p.y) * h[(size_t)p.x * DFEAT + lane];
    }
    agg[(size_t)n * DFEAT + lane] = acc;
}

// ---- epilogue: register-resident W, readlane broadcast, grid-stride rows ----
__global__ __launch_bounds__(256) void epilogue_kernel(
    const float* __restrict__ agg, const float* __restrict__ ifeat,
    const float* __restrict__ weight,   // [128][64] row-major
    const float* __restrict__ lamda_p, const float* __restrict__ alpha_p,
    const int* __restrict__ layer_p,
    float* __restrict__ out, int N, int total_waves) {
    int lane = threadIdx.x & 63;
    int wave = (blockIdx.x * 256 + threadIdx.x) >> 6;

    // lane j holds column j of W: wreg[k] = W[k][j], k = 0..127 (128 VGPRs)
    float wreg[128];
#pragma unroll
    for (int k = 0; k < 128; ++k) wreg[k] = weight[k * DFEAT + lane];

    float lam = lamda_p[0];
    float alpha = alpha_p[0];
    float theta = fminf(1.0f, logf(lam / (float)layer_p[0] + 1.0f));

    for (int r = wave; r < N; r += total_waves) {
        float hv = agg[(size_t)r * DFEAT + lane];
        float iv = ifeat[(size_t)r * DFEAT + lane];
        float acc = 0.f;
#pragma unroll
        for (int k = 0; k < 64; ++k)
            acc += lane_bcast(hv, k) * wreg[k];
#pragma unroll
        for (int k = 0; k < 64; ++k)
            acc += lane_bcast(iv, k) * wreg[64 + k];
        out[(size_t)r * DFEAT + lane] =
            theta * acc + (1.f - theta) * ((1.f - alpha) * hv + alpha * iv) + iv;
    }
}

extern "C" void kernel_launch(void* const* d_in, const int* in_sizes, int n_in,
                              void* d_out, int out_size, void* d_ws, size_t ws_size,
                              hipStream_t stream) {
    const float* h       = (const float*)d_in[0];
    const float* ifeat   = (const float*)d_in[1];
    const float* weight  = (const float*)d_in[2];
    const float* edge_w  = (const float*)d_in[3];
    const float* lamda_p = (const float*)d_in[4];
    const float* alpha_p = (const float*)d_in[5];
    const int*   e_src   = (const int*)d_in[6];
    const int*   e_dst   = (const int*)d_in[7];
    const int*   layer_p = (const int*)d_in[8];
    float* out = (float*)d_out;

    int N = in_sizes[0] / DFEAT;
    int E = in_sizes[3];

    // workspace layout (bytes)
    char* ws = (char*)d_ws;
    float* agg    = (float*)ws;                          // N*64 f32 = 25.6 MB
    int*   deg    = (int*)(ws + (size_t)N * DFEAT * 4);  // N int
    int*   cursor = deg + N;                             // N int
    int*   bsum   = cursor + N;                          // 256 int
    int2*  packed = (int2*)((char*)(bsum + 256) + ((16 - (((size_t)(bsum + 256)) & 15)) & 15)); // E*8 B

    // 1. zero degree counters (ws is re-poisoned to 0xAA before every call)
    hipMemsetAsync(deg, 0, (size_t)N * sizeof(int), stream);

    // 2. degree histogram
    hist_kernel<<<(E + 255) / 256, 256, 0, stream>>>(e_dst, deg, E);

    // 3-5. exclusive scan -> cursor (CSR offsets)
    int nb = (N + 1023) / 1024;
    scan_block_kernel<<<nb, 1024, 0, stream>>>(deg, cursor, bsum, N);
    scan_top_kernel<<<1, 128, 0, stream>>>(bsum, nb);
    apply_kernel<<<(N + 255) / 256, 256, 0, stream>>>(cursor, bsum, N);

    // 6. bucket-fill packed edges (cursor[n] ends at start+deg)
    fill_kernel<<<(E + 255) / 256, 256, 0, stream>>>(
        e_src, e_dst, edge_w, cursor, packed, E);

    // 7. gather SpMM: one wave per node
    gather_kernel<<<(N + 3) / 4, 256, 0, stream>>>(
        h, packed, cursor, deg, agg, N);

    // 8. epilogue GEMM + mix + residual: 768 blocks * 4 waves = 3072 waves
    int epi_blocks = 768;
    int total_waves = epi_blocks * 4;
    epilogue_kernel<<<epi_blocks, 256, 0, stream>>>(
        agg, ifeat, weight, lamda_p, alpha_p, layer_p, out, N, total_waves);
}